// Round 1
// baseline (1121.426 us; speedup 1.0000x reference)
//
#include <hip/hip_runtime.h>
#include <hip/hip_bf16.h>
#include <math.h>

// DAWN block, fp32 baseline.
// B=4 S=1024 D=1024 H=16 DH=64 R=128 NC=NE=64 NK=4096 KR=128 TOPK=8
// Workspace requirement: ~153 MB (see layout in kernel_launch).

#define B_    4
#define S_    1024
#define D_    1024
#define H_    16
#define DH_   64
#define R_    128
#define NN_   64      // routers' expert count (NC == NE == 64)
#define NK_   4096
#define TOPK_ 8

// ---------------------------------------------------------------------------
// LayerNorm: one block per token, 256 threads x float4.
// ---------------------------------------------------------------------------
__global__ __launch_bounds__(256) void layernorm_kernel(
    const float* __restrict__ x, const float* __restrict__ g,
    const float* __restrict__ bsh, float* __restrict__ out)
{
  const long row = blockIdx.x;
  const int tid = threadIdx.x;
  const float4 v = reinterpret_cast<const float4*>(x + row * D_)[tid];
  float s = v.x + v.y + v.z + v.w;
  #pragma unroll
  for (int m = 1; m < 64; m <<= 1) s += __shfl_xor(s, m);
  __shared__ float red1[4], red2[4];
  if ((tid & 63) == 0) red1[tid >> 6] = s;
  __syncthreads();
  const float mean = (red1[0] + red1[1] + red1[2] + red1[3]) * (1.0f / D_);
  const float dx = v.x - mean, dy = v.y - mean, dz = v.z - mean, dw = v.w - mean;
  float s2 = dx * dx + dy * dy + dz * dz + dw * dw;
  #pragma unroll
  for (int m = 1; m < 64; m <<= 1) s2 += __shfl_xor(s2, m);
  if ((tid & 63) == 0) red2[tid >> 6] = s2;
  __syncthreads();
  const float var = (red2[0] + red2[1] + red2[2] + red2[3]) * (1.0f / D_);
  const float inv = 1.0f / sqrtf(var + 1e-5f);
  const float4 gg = reinterpret_cast<const float4*>(g)[tid];
  const float4 bb = reinterpret_cast<const float4*>(bsh)[tid];
  float4 o;
  o.x = dx * inv * gg.x + bb.x;
  o.y = dy * inv * gg.y + bb.y;
  o.z = dz * inv * gg.z + bb.z;
  o.w = dw * inv * gg.w + bb.w;
  reinterpret_cast<float4*>(out + row * D_)[tid] = o;
}

// ---------------------------------------------------------------------------
// Build transposed router weights: out[j][r][n] = Wr[n*D + j]
// ---------------------------------------------------------------------------
__global__ void build_wt_kernel(const float* __restrict__ W0, const float* __restrict__ W1,
                                const float* __restrict__ W2, const float* __restrict__ W3,
                                float* __restrict__ out, int nr)
{
  const int idx = blockIdx.x * 256 + threadIdx.x;
  const int cols = nr * NN_;
  const int j = idx / cols;
  const int rem = idx - j * cols;
  const int r = rem >> 6, n = rem & 63;
  const float* W = (r == 0) ? W0 : (r == 1) ? W1 : (r == 2) ? W2 : W3;
  out[idx] = W[n * D_ + j];
}

// ---------------------------------------------------------------------------
// Router (4 routers fused): 8 tokens per block. Wave r handles router r,
// lane n handles expert n. Softmax over lanes, importance-weighted pooling
// pre-reduced over the 8 tokens, one atomicAdd per thread.
// wacc layout: [router][B][64]
// ---------------------------------------------------------------------------
__global__ __launch_bounds__(256) void router4_kernel(
    const float* __restrict__ nx, const float* __restrict__ imp,
    const float* __restrict__ WT /*[D][4*64]*/, float* __restrict__ wacc)
{
  __shared__ __align__(16) float xr[8][D_];
  const int blkPerB = S_ / 8;
  const int b = blockIdx.x / blkPerB;
  const int s0 = (blockIdx.x % blkPerB) * 8;
  const int tid = threadIdx.x;
  const float4* src = reinterpret_cast<const float4*>(nx + ((long)b * S_ + s0) * D_);
  float4* dst = reinterpret_cast<float4*>(&xr[0][0]);
  #pragma unroll
  for (int i = 0; i < 8; ++i) dst[tid + i * 256] = src[tid + i * 256];
  __syncthreads();
  const int r = tid >> 6, n = tid & 63;
  float acc[8] = {0, 0, 0, 0, 0, 0, 0, 0};
  for (int j4 = 0; j4 < D_ / 4; ++j4) {
    float xv[8][4];
    #pragma unroll
    for (int t = 0; t < 8; ++t) {
      const float4 v = *reinterpret_cast<const float4*>(&xr[t][j4 * 4]);
      xv[t][0] = v.x; xv[t][1] = v.y; xv[t][2] = v.z; xv[t][3] = v.w;
    }
    #pragma unroll
    for (int q = 0; q < 4; ++q) {
      const float wv = WT[(j4 * 4 + q) * 256 + tid];
      #pragma unroll
      for (int t = 0; t < 8; ++t) acc[t] += xv[t][q] * wv;
    }
  }
  float total = 0.0f;
  #pragma unroll
  for (int t = 0; t < 8; ++t) {
    float v = acc[t];
    float mx = v;
    #pragma unroll
    for (int m = 32; m; m >>= 1) mx = fmaxf(mx, __shfl_xor(mx, m));
    const float e = __expf(v - mx);
    float sum = e;
    #pragma unroll
    for (int m = 32; m; m >>= 1) sum += __shfl_xor(sum, m);
    const float pref = e / sum;
    total += imp[(long)b * S_ + s0 + t] * pref;
  }
  atomicAdd(&wacc[((long)r * B_ + b) * NN_ + n], total);
}

// Single-router variant (memory router): 4 waves each handle 2 of 8 tokens.
__global__ __launch_bounds__(256) void router1_kernel(
    const float* __restrict__ nx, const float* __restrict__ imp,
    const float* __restrict__ WT /*[D][64]*/, float* __restrict__ wacc /*[B][64]*/)
{
  __shared__ __align__(16) float xr[8][D_];
  const int blkPerB = S_ / 8;
  const int b = blockIdx.x / blkPerB;
  const int s0 = (blockIdx.x % blkPerB) * 8;
  const int tid = threadIdx.x;
  const float4* src = reinterpret_cast<const float4*>(nx + ((long)b * S_ + s0) * D_);
  float4* dst = reinterpret_cast<float4*>(&xr[0][0]);
  #pragma unroll
  for (int i = 0; i < 8; ++i) dst[tid + i * 256] = src[tid + i * 256];
  __syncthreads();
  const int w = tid >> 6, n = tid & 63;
  const int t0 = w * 2, t1 = w * 2 + 1;
  float acc0 = 0.0f, acc1 = 0.0f;
  for (int j4 = 0; j4 < D_ / 4; ++j4) {
    const float4 v0 = *reinterpret_cast<const float4*>(&xr[t0][j4 * 4]);
    const float4 v1 = *reinterpret_cast<const float4*>(&xr[t1][j4 * 4]);
    const float w0 = WT[(j4 * 4 + 0) * NN_ + n];
    const float w1 = WT[(j4 * 4 + 1) * NN_ + n];
    const float w2 = WT[(j4 * 4 + 2) * NN_ + n];
    const float w3 = WT[(j4 * 4 + 3) * NN_ + n];
    acc0 += v0.x * w0 + v0.y * w1 + v0.z * w2 + v0.w * w3;
    acc1 += v1.x * w0 + v1.y * w1 + v1.z * w2 + v1.w * w3;
  }
  float total = 0.0f;
  #pragma unroll
  for (int t = 0; t < 2; ++t) {
    const float v = (t == 0) ? acc0 : acc1;
    float mx = v;
    #pragma unroll
    for (int m = 32; m; m >>= 1) mx = fmaxf(mx, __shfl_xor(mx, m));
    const float e = __expf(v - mx);
    float sum = e;
    #pragma unroll
    for (int m = 32; m; m >>= 1) sum += __shfl_xor(sum, m);
    total += imp[(long)b * S_ + s0 + ((t == 0) ? t0 : t1)] * (e / sum);
  }
  atomicAdd(&wacc[(long)b * NN_ + n], total);
}

// Normalize pooled router weights: one block per (slot,b), 64 threads.
__global__ void norm_w_kernel(float* __restrict__ w)
{
  const int base = blockIdx.x * NN_;
  const int tid = threadIdx.x;
  const float v = w[base + tid];
  float s = v;
  #pragma unroll
  for (int m = 32; m; m >>= 1) s += __shfl_xor(s, m);
  w[base + tid] = v / (s + 1e-8f);
}

// ---------------------------------------------------------------------------
// Weighted pool sum: out[(j*B+b)*elems + i] = sum_n w[(j*B+b)*64+n]*pool[n*elems+i]
// ---------------------------------------------------------------------------
template <int NW>
__global__ __launch_bounds__(256) void wsum_kernel(
    const float* __restrict__ pool, const float* __restrict__ w,
    float* __restrict__ out, long elems)
{
  __shared__ float wl[NW * B_ * NN_];
  const int tid = threadIdx.x;
  for (int i = tid; i < NW * B_ * NN_; i += 256) wl[i] = w[i];
  __syncthreads();
  const long i = (long)blockIdx.x * 256 + tid;
  float acc[NW][B_];
  #pragma unroll
  for (int j = 0; j < NW; ++j)
    #pragma unroll
    for (int b = 0; b < B_; ++b) acc[j][b] = 0.0f;
  for (int n = 0; n < NN_; ++n) {
    const float p = pool[n * elems + i];
    #pragma unroll
    for (int j = 0; j < NW; ++j)
      #pragma unroll
      for (int b = 0; b < B_; ++b) acc[j][b] += wl[(j * B_ + b) * NN_ + n] * p;
  }
  #pragma unroll
  for (int j = 0; j < NW; ++j)
    #pragma unroll
    for (int b = 0; b < B_; ++b)
      out[(long)(j * B_ + b) * elems + i] = acc[j][b];
}

// ---------------------------------------------------------------------------
// Generic tiled fp32 GEMM: C[b] = scale*(A[b] @ B[b]) (+ addsrc[b]).
// A: M x K row-major (lda=K), B: K x N row-major (ldb=N), C/addsrc: M x N.
// 64x64 tile, 256 threads (16x16), 4x4 per thread, TK=16.
// grid: (N/64, M/64, batch)
// ---------------------------------------------------------------------------
__global__ __launch_bounds__(256) void gemm_f32(
    const float* __restrict__ A, const float* __restrict__ Bm,
    float* __restrict__ C, const float* __restrict__ addsrc,
    int M, int N, int K, long sA, long sB, long sC, long sAdd, float scale)
{
  const int bz = blockIdx.z;
  A += (long)bz * sA;
  Bm += (long)bz * sB;
  C += (long)bz * sC;
  if (addsrc) addsrc += (long)bz * sAdd;
  const int n0 = blockIdx.x * 64, m0 = blockIdx.y * 64;
  __shared__ __align__(16) float As[16][68];
  __shared__ __align__(16) float Bs[16][64];
  const int tid = threadIdx.x;
  const int tx = tid & 15, ty = tid >> 4;
  const int mA = tid >> 2, kA4 = (tid & 3) * 4;   // A tile: 64 rows x 16 k
  const int kB = tid >> 4, nB4 = (tid & 15) * 4;  // B tile: 16 k x 64 n
  float acc[4][4] = {};
  for (int kt = 0; kt < K; kt += 16) {
    const float4 av = *reinterpret_cast<const float4*>(&A[(long)(m0 + mA) * K + kt + kA4]);
    const float4 bv = *reinterpret_cast<const float4*>(&Bm[(long)(kt + kB) * N + n0 + nB4]);
    __syncthreads();
    As[kA4 + 0][mA] = av.x;
    As[kA4 + 1][mA] = av.y;
    As[kA4 + 2][mA] = av.z;
    As[kA4 + 3][mA] = av.w;
    *reinterpret_cast<float4*>(&Bs[kB][nB4]) = bv;
    __syncthreads();
    #pragma unroll
    for (int k = 0; k < 16; ++k) {
      const float4 a4 = *reinterpret_cast<const float4*>(&As[k][ty * 4]);
      const float4 b4 = *reinterpret_cast<const float4*>(&Bs[k][tx * 4]);
      acc[0][0] += a4.x * b4.x; acc[0][1] += a4.x * b4.y; acc[0][2] += a4.x * b4.z; acc[0][3] += a4.x * b4.w;
      acc[1][0] += a4.y * b4.x; acc[1][1] += a4.y * b4.y; acc[1][2] += a4.y * b4.z; acc[1][3] += a4.y * b4.w;
      acc[2][0] += a4.z * b4.x; acc[2][1] += a4.z * b4.y; acc[2][2] += a4.z * b4.z; acc[2][3] += a4.z * b4.w;
      acc[3][0] += a4.w * b4.x; acc[3][1] += a4.w * b4.y; acc[3][2] += a4.w * b4.z; acc[3][3] += a4.w * b4.w;
    }
  }
  #pragma unroll
  for (int i = 0; i < 4; ++i) {
    const long m = m0 + ty * 4 + i;
    const long off = m * N + n0 + tx * 4;
    float4 r;
    r.x = acc[i][0] * scale; r.y = acc[i][1] * scale;
    r.z = acc[i][2] * scale; r.w = acc[i][3] * scale;
    if (addsrc) {
      const float4 s4 = *reinterpret_cast<const float4*>(&addsrc[off]);
      r.x += s4.x; r.y += s4.y; r.z += s4.z; r.w += s4.w;
    }
    *reinterpret_cast<float4*>(&C[off]) = r;
  }
}

// ---------------------------------------------------------------------------
// Tiled transpose: out[c][r] = in[r][c] (rows,cols multiples of 32)
// ---------------------------------------------------------------------------
__global__ void transpose_kernel(const float* __restrict__ in, float* __restrict__ out,
                                 int rows, int cols)
{
  __shared__ float t[32][33];
  const int bx = blockIdx.x * 32, by = blockIdx.y * 32;
  #pragma unroll
  for (int i = threadIdx.y; i < 32; i += 8)
    t[i][threadIdx.x] = in[(long)(by + i) * cols + bx + threadIdx.x];
  __syncthreads();
  #pragma unroll
  for (int i = threadIdx.y; i < 32; i += 8)
    out[(long)(bx + i) * rows + by + threadIdx.x] = t[threadIdx.x][i];
}

// ---------------------------------------------------------------------------
// Flash attention fp32, causal. Block per (qtile=64 rows, head, batch).
// Q/K/V in [B][S][D] layout with head packing d = h*64+dh.
// LDS: Qs/KPs (transposed [dh][row]) + Vs ([row][dh]); P reuses KPs.
// ---------------------------------------------------------------------------
__global__ __launch_bounds__(256) void flash_kernel(
    const float* __restrict__ Q, const float* __restrict__ K,
    const float* __restrict__ V, float* __restrict__ O)
{
  const int qt = blockIdx.x, h = blockIdx.y, b = blockIdx.z;
  const int q0 = qt * 64;
  const long base = (long)b * S_ * D_ + h * DH_;
  __shared__ __align__(16) float Qs[64][68];
  __shared__ __align__(16) float KPs[64][68];
  __shared__ __align__(16) float Vs[64][68];
  const int tid = threadIdx.x;
  const int tx = tid & 15, ty = tid >> 4;
  #pragma unroll
  for (int i = 0; i < 16; ++i) {
    const int idx = tid + i * 256;
    const int row = idx >> 6, dh = idx & 63;
    Qs[dh][row] = Q[base + (long)(q0 + row) * D_ + dh];
  }
  float m_r[4], l_r[4], oa[4][4];
  #pragma unroll
  for (int i = 0; i < 4; ++i) {
    m_r[i] = -1e30f; l_r[i] = 0.0f;
    #pragma unroll
    for (int j = 0; j < 4; ++j) oa[i][j] = 0.0f;
  }
  for (int kt = 0; kt <= qt; ++kt) {
    const int k0 = kt * 64;
    __syncthreads();
    #pragma unroll
    for (int i = 0; i < 16; ++i) {
      const int idx = tid + i * 256;
      const int row = idx >> 6, dh = idx & 63;
      KPs[dh][row] = K[base + (long)(k0 + row) * D_ + dh];
      Vs[row][dh] = V[base + (long)(k0 + row) * D_ + dh];
    }
    __syncthreads();
    float sc[4][4] = {};
    #pragma unroll 8
    for (int dh = 0; dh < 64; ++dh) {
      const float4 qv = *reinterpret_cast<const float4*>(&Qs[dh][ty * 4]);
      const float4 kv = *reinterpret_cast<const float4*>(&KPs[dh][tx * 4]);
      sc[0][0] += qv.x * kv.x; sc[0][1] += qv.x * kv.y; sc[0][2] += qv.x * kv.z; sc[0][3] += qv.x * kv.w;
      sc[1][0] += qv.y * kv.x; sc[1][1] += qv.y * kv.y; sc[1][2] += qv.y * kv.z; sc[1][3] += qv.y * kv.w;
      sc[2][0] += qv.z * kv.x; sc[2][1] += qv.z * kv.y; sc[2][2] += qv.z * kv.z; sc[2][3] += qv.z * kv.w;
      sc[3][0] += qv.w * kv.x; sc[3][1] += qv.w * kv.y; sc[3][2] += qv.w * kv.z; sc[3][3] += qv.w * kv.w;
    }
    const bool diag = (kt == qt);
    #pragma unroll
    for (int i = 0; i < 4; ++i) {
      #pragma unroll
      for (int j = 0; j < 4; ++j) {
        float v = sc[i][j] * 0.125f;  // 1/sqrt(64)
        if (diag && (tx * 4 + j > ty * 4 + i)) v = -1e30f;
        sc[i][j] = v;
      }
    }
    #pragma unroll
    for (int i = 0; i < 4; ++i) {
      float rm = fmaxf(fmaxf(sc[i][0], sc[i][1]), fmaxf(sc[i][2], sc[i][3]));
      #pragma unroll
      for (int m = 1; m < 16; m <<= 1) rm = fmaxf(rm, __shfl_xor(rm, m, 16));
      const float mnew = fmaxf(m_r[i], rm);
      const float alpha = __expf(m_r[i] - mnew);
      m_r[i] = mnew;
      float rs = 0.0f;
      #pragma unroll
      for (int j = 0; j < 4; ++j) {
        const float p = __expf(sc[i][j] - mnew);
        sc[i][j] = p; rs += p;
      }
      #pragma unroll
      for (int m = 1; m < 16; m <<= 1) rs += __shfl_xor(rs, m, 16);
      l_r[i] = l_r[i] * alpha + rs;
      #pragma unroll
      for (int j = 0; j < 4; ++j) oa[i][j] *= alpha;
    }
    __syncthreads();  // done reading KPs (K tile) -> overwrite with P
    #pragma unroll
    for (int i = 0; i < 4; ++i)
      #pragma unroll
      for (int j = 0; j < 4; ++j) KPs[ty * 4 + i][tx * 4 + j] = sc[i][j];
    __syncthreads();
    #pragma unroll
    for (int kk = 0; kk < 16; ++kk) {
      float4 vv[4];
      #pragma unroll
      for (int q = 0; q < 4; ++q)
        vv[q] = *reinterpret_cast<const float4*>(&Vs[kk * 4 + q][tx * 4]);
      #pragma unroll
      for (int i = 0; i < 4; ++i) {
        const float4 pv = *reinterpret_cast<const float4*>(&KPs[ty * 4 + i][kk * 4]);
        oa[i][0] += pv.x * vv[0].x + pv.y * vv[1].x + pv.z * vv[2].x + pv.w * vv[3].x;
        oa[i][1] += pv.x * vv[0].y + pv.y * vv[1].y + pv.z * vv[2].y + pv.w * vv[3].y;
        oa[i][2] += pv.x * vv[0].z + pv.y * vv[1].z + pv.z * vv[2].z + pv.w * vv[3].z;
        oa[i][3] += pv.x * vv[0].w + pv.y * vv[1].w + pv.z * vv[2].w + pv.w * vv[3].w;
      }
    }
  }
  #pragma unroll
  for (int i = 0; i < 4; ++i) {
    const float inv = 1.0f / l_r[i];
    float4 o;
    o.x = oa[i][0] * inv; o.y = oa[i][1] * inv;
    o.z = oa[i][2] * inv; o.w = oa[i][3] * inv;
    *reinterpret_cast<float4*>(&O[base + (long)(q0 + ty * 4 + i) * D_ + tx * 4]) = o;
  }
}

// ---------------------------------------------------------------------------
// Top-8 over 4096 knowledge scores per token + softmax + V gather + residual.
// In-place on xo (== d_out).
// ---------------------------------------------------------------------------
__global__ __launch_bounds__(256) void topk_mem_kernel(
    const float* __restrict__ ks, const float* __restrict__ kV,
    float* __restrict__ xo)
{
  __shared__ float vals[NK_];
  __shared__ float wmax_s[4];
  __shared__ int widx_s[4];
  __shared__ float selv[TOPK_];
  __shared__ int seli[TOPK_];
  const long row = blockIdx.x;
  const int tid = threadIdx.x;
  const float4* src = reinterpret_cast<const float4*>(ks + row * NK_);
  float4* vdst = reinterpret_cast<float4*>(vals);
  #pragma unroll
  for (int i = 0; i < 4; ++i) vdst[tid + i * 256] = src[tid + i * 256];
  __syncthreads();
  for (int it = 0; it < TOPK_; ++it) {
    float bm = -1e38f;
    int bi = 0x7fffffff;
    #pragma unroll
    for (int i = 0; i < 16; ++i) {
      const int idx = i * 256 + tid;
      const float v = vals[idx];
      if (v > bm) { bm = v; bi = idx; }  // scan in increasing idx: ties keep lower
    }
    #pragma unroll
    for (int m = 1; m < 64; m <<= 1) {
      const float ov = __shfl_xor(bm, m);
      const int oi = __shfl_xor(bi, m);
      if (ov > bm || (ov == bm && oi < bi)) { bm = ov; bi = oi; }
    }
    if ((tid & 63) == 0) { wmax_s[tid >> 6] = bm; widx_s[tid >> 6] = bi; }
    __syncthreads();
    if (tid == 0) {
      float v = wmax_s[0]; int vi = widx_s[0];
      for (int wv = 1; wv < 4; ++wv)
        if (wmax_s[wv] > v || (wmax_s[wv] == v && widx_s[wv] < vi)) { v = wmax_s[wv]; vi = widx_s[wv]; }
      selv[it] = v; seli[it] = vi;
      vals[vi] = -1e38f;
    }
    __syncthreads();
  }
  float w8[TOPK_];
  float wsum = 0.0f;
  #pragma unroll
  for (int k = 0; k < TOPK_; ++k) { w8[k] = __expf(selv[k] - selv[0]); wsum += w8[k]; }
  const float inv = 1.0f / wsum;
  const int d0 = tid * 4;
  float4 o = *reinterpret_cast<const float4*>(&xo[row * D_ + d0]);
  #pragma unroll
  for (int k = 0; k < TOPK_; ++k) {
    const float4 vv = *reinterpret_cast<const float4*>(&kV[(long)seli[k] * D_ + d0]);
    const float wk = w8[k] * inv;
    o.x += wk * vv.x; o.y += wk * vv.y; o.z += wk * vv.z; o.w += wk * vv.w;
  }
  *reinterpret_cast<float4*>(&xo[row * D_ + d0]) = o;
}

// ---------------------------------------------------------------------------
extern "C" void kernel_launch(void* const* d_in, const int* in_sizes, int n_in,
                              void* d_out, int out_size, void* d_ws, size_t ws_size,
                              hipStream_t stream)
{
  const float* x   = (const float*)d_in[0];
  const float* imp = (const float*)d_in[1];
  // d_in[2] is the causal mask -> ignored (computed arithmetically)
  const float* CN  = (const float*)d_in[3];   // [64][1024][128]
  const float* EP  = (const float*)d_in[4];   // [64][128][1024]
  const float* kK  = (const float*)d_in[5];   // [4096][128]
  const float* kV  = (const float*)d_in[6];   // [4096][1024]
  const float* Wc  = (const float*)d_in[7];
  const float* WQ  = (const float*)d_in[8];
  const float* WK  = (const float*)d_in[9];
  const float* WV  = (const float*)d_in[10];
  const float* Wm  = (const float*)d_in[11];
  const float* WO  = (const float*)d_in[12];  // [1024][1024]
  const float* g1  = (const float*)d_in[13];
  const float* b1  = (const float*)d_in[14];
  const float* g2  = (const float*)d_in[15];
  const float* b2  = (const float*)d_in[16];
  float* out = (float*)d_out;
  float* ws = (float*)d_ws;

  const long BSD = (long)B_ * S_ * D_;      // 4 Mi floats
  const long BSR = (long)B_ * S_ * R_;      // 512 Ki
  const long DR  = (long)D_ * R_;           // 128 Ki
  const long RD  = DR;

  // workspace layout (floats); total ~38.1 Mi floats ~ 153 MB
  float* nx_attn = ws;                       // BSD : nx, then attn_out
  float* Qb   = nx_attn + BSD;               // BSD : Q, then nx2
  float* Kb   = Qb + BSD;                    // BSD
  float* Vb   = Kb + BSD;                    // BSD
  float* ksc  = Vb + BSD;                    // B*S*NK = 16 Mi
  float* hb   = ksc + (long)B_ * S_ * NK_;   // BSR : h, then Qm
  float* scb  = hb + BSR;                    // B*DR : sc, then scm
  float* eQKV = scb + (long)B_ * DR;         // 3*B*RD
  float* WOt  = eQKV + 3L * B_ * RD;         // 1 Mi
  float* kKt  = WOt + (long)D_ * D_;         // 512 Ki
  float* WT4  = kKt + (long)NK_ * R_;        // 1024*256
  float* WTm  = WT4 + (long)D_ * 4 * NN_;    // 1024*64
  float* wacc = WTm + (long)D_ * NN_;        // 5*B*64

  // --- prep ---
  hipMemsetAsync(wacc, 0, 5 * B_ * NN_ * sizeof(float), stream);
  build_wt_kernel<<<(D_ * 4 * NN_) / 256, 256, 0, stream>>>(Wc, WQ, WK, WV, WT4, 4);
  build_wt_kernel<<<(D_ * NN_) / 256, 256, 0, stream>>>(Wm, Wm, Wm, Wm, WTm, 1);
  transpose_kernel<<<dim3(D_ / 32, D_ / 32), dim3(32, 8), 0, stream>>>(WO, WOt, D_, D_);
  transpose_kernel<<<dim3(R_ / 32, NK_ / 32), dim3(32, 8), 0, stream>>>(kK, kKt, NK_, R_);

  // --- attention sub-block ---
  layernorm_kernel<<<B_ * S_, 256, 0, stream>>>(x, g1, b1, nx_attn);
  router4_kernel<<<B_ * S_ / 8, 256, 0, stream>>>(nx_attn, imp, WT4, wacc);
  norm_w_kernel<<<4 * B_, 64, 0, stream>>>(wacc);
  wsum_kernel<1><<<DR / 256, 256, 0, stream>>>(CN, wacc, scb, DR);
  wsum_kernel<3><<<RD / 256, 256, 0, stream>>>(EP, wacc + (long)1 * B_ * NN_, eQKV, RD);
  // h = nx @ sc  [1024x1024]x[1024x128]
  gemm_f32<<<dim3(R_ / 64, S_ / 64, B_), 256, 0, stream>>>(
      nx_attn, scb, hb, nullptr, S_, R_, D_, (long)S_ * D_, DR, (long)S_ * R_, 0, 1.0f);
  // Q/K/V = h @ e{Q,K,V}  [1024x128]x[128x1024]
  gemm_f32<<<dim3(D_ / 64, S_ / 64, B_), 256, 0, stream>>>(
      hb, eQKV + 0L * B_ * RD, Qb, nullptr, S_, D_, R_, (long)S_ * R_, RD, (long)S_ * D_, 0, 1.0f);
  gemm_f32<<<dim3(D_ / 64, S_ / 64, B_), 256, 0, stream>>>(
      hb, eQKV + 1L * B_ * RD, Kb, nullptr, S_, D_, R_, (long)S_ * R_, RD, (long)S_ * D_, 0, 1.0f);
  gemm_f32<<<dim3(D_ / 64, S_ / 64, B_), 256, 0, stream>>>(
      hb, eQKV + 2L * B_ * RD, Vb, nullptr, S_, D_, R_, (long)S_ * R_, RD, (long)S_ * D_, 0, 1.0f);
  // flash attention -> attn_out (reuses nx buffer)
  flash_kernel<<<dim3(S_ / 64, H_, B_), 256, 0, stream>>>(Qb, Kb, Vb, nx_attn);
  // x2 = attn_out @ WO.T + x  -> d_out
  gemm_f32<<<dim3(D_ / 64, (B_ * S_) / 64, 1), 256, 0, stream>>>(
      nx_attn, WOt, out, x, B_ * S_, D_, D_, 0, 0, 0, 0, 1.0f);

  // --- memory sub-block ---
  layernorm_kernel<<<B_ * S_, 256, 0, stream>>>(out, g2, b2, Qb);  // nx2 in Qb
  router1_kernel<<<B_ * S_ / 8, 256, 0, stream>>>(Qb, imp, WTm, wacc + 4L * B_ * NN_);
  norm_w_kernel<<<B_, 64, 0, stream>>>(wacc + 4L * B_ * NN_);
  wsum_kernel<1><<<DR / 256, 256, 0, stream>>>(CN, wacc + 4L * B_ * NN_, scb, DR);
  // Qm = nx2 @ scm
  gemm_f32<<<dim3(R_ / 64, S_ / 64, B_), 256, 0, stream>>>(
      Qb, scb, hb, nullptr, S_, R_, D_, (long)S_ * D_, DR, (long)S_ * R_, 0, 1.0f);
  // kscores = Qm @ kK.T / sqrt(128)
  gemm_f32<<<dim3(NK_ / 64, S_ / 64, B_), 256, 0, stream>>>(
      hb, kKt, ksc, nullptr, S_, NK_, R_, (long)S_ * R_, 0, (long)S_ * NK_, 0,
      0.08838834764831845f);
  // top-8 + softmax + gather + residual (in-place on d_out)
  topk_mem_kernel<<<B_ * S_, 256, 0, stream>>>(ksc, kV, out);
}